// Round 18
// baseline (101.546 us; speedup 1.0000x reference)
//
#include <hip/hip_runtime.h>
#include <math.h>

#define NB 32
#define NT 128
#define KD 16

// ws byte offsets
#define PKH_OFF  0u          // f16 [32][128][64] 512 KB
#define PVT_OFF  524288u     // f16 [32][64][128] 512 KB (o-major)
#define W1P_OFF  1048576u    // bf16 MFMA frags [3*16][64] uint4, 48 KB
#define W2P_OFF  1097728u    // bf16 MFMA frags [8*16][64] uint4, 128 KB
#define FLAG_OFF 2097152u    // u32 barrier counter (memset to 0 pre-launch)

typedef float f32x4 __attribute__((ext_vector_type(4)));
typedef short bf16x8 __attribute__((ext_vector_type(8)));
typedef __fp16 f16x2 __attribute__((ext_vector_type(2)));
union U4B8 { uint4 u; bf16x8 h; };
union U4H8 { uint4 u; f16x2 h[4]; };

// LDS map (50048 B -> 2 blocks/CU)
#define L_PK 0        // f16 [128][72] = 18432 ; aliased by H1/H2 after syncA
#define L_PV 18432    // f16 [64][136] = 17408 (ends 35840)
#define L_P  35840    // f16 [32][136] = 8704  (ends 44544)
#define L_X  44544    // bf16 [16][104] = 3328 (ends 47872)
#define L_Q  47872    // f32 [8][68] = 2176 (ends 50048) -- written phase A
#define L_TOT 50048
#define L_H1 0        // bf16 [16][264] = 8448
#define L_H2 8448     // ends 16896 <= 18432 (inside dead Pk)

__device__ __forceinline__ unsigned short bf16rne(float f) {
    unsigned u = __float_as_uint(f);
    return (unsigned short)((u + 0x7fffu + ((u >> 16) & 1u)) >> 16);
}
__device__ __forceinline__ void unpack8(uint4 u, float* f) {
    f[0] = __uint_as_float(u.x << 16); f[1] = __uint_as_float(u.x & 0xffff0000u);
    f[2] = __uint_as_float(u.y << 16); f[3] = __uint_as_float(u.y & 0xffff0000u);
    f[4] = __uint_as_float(u.z << 16); f[5] = __uint_as_float(u.z & 0xffff0000u);
    f[6] = __uint_as_float(u.w << 16); f[7] = __uint_as_float(u.w & 0xffff0000u);
}
__device__ __forceinline__ f16x2 pkmax(f16x2 a, f16x2 b) {
    f16x2 d;
    asm("v_pk_max_f16 %0, %1, %2" : "=v"(d) : "v"(a), "v"(b));
    return d;
}
#if __has_builtin(__builtin_amdgcn_fdot2)
#define FDOT2(a, b, c) __builtin_amdgcn_fdot2((a), (b), (c), false)
#else
#define FDOT2(a, b, c) ((c) + (float)(a)[0] * (float)(b)[0] + (float)(a)[1] * (float)(b)[1])
#endif

__global__ __launch_bounds__(512, 4) void actor_kernel(
    const float* __restrict__ state, const float* __restrict__ eps,
    const float* __restrict__ Wq, const float* __restrict__ bq,
    const float* __restrict__ Wk, const float* __restrict__ bkg,
    const float* __restrict__ Wv, const float* __restrict__ bvg,
    const float* __restrict__ W1, const float* __restrict__ b1g,
    const float* __restrict__ W2, const float* __restrict__ b2g,
    const float* __restrict__ Wmu, const float* __restrict__ bmu,
    const float* __restrict__ Wls, const float* __restrict__ bls,
    char* __restrict__ wsb, float* __restrict__ out)
{
    __shared__ __align__(16) char sm[L_TOT];

    const int tid = threadIdx.x, w = tid >> 6, lane = tid & 63;
    const int bid = blockIdx.x;
    const int b    = (bid & 7) * 4 + ((bid >> 3) >> 4);  // batch -> fixed XCD slot
    const int tile = (bid >> 3) & 15;
    const int iloc = tile * 8 + w;
    const int row  = b * NT + iloc;
    const int h = lane >> 4, s = lane & 15;
    const int g = h, lr = s;
    const int t0 = 2 * w;
    const int n0 = w * 32 + lr, n1 = n0 + 16;

    unsigned short* PkH = (unsigned short*)(wsb + PKH_OFF);
    unsigned short* PvT = (unsigned short*)(wsb + PVT_OFF);
    unsigned* flagp = (unsigned*)(wsb + FLAG_OFF);

    // ======== PHASE A: own 8 rows' projections + W-pack share ========
    {
        float sreg[16];
        {
            const float4* srow = (const float4*)(state + (size_t)row * KD);
            #pragma unroll
            for (int r4 = 0; r4 < 4; ++r4) {
                float4 v = srow[r4];
                sreg[r4*4+0]=v.x; sreg[r4*4+1]=v.y; sreg[r4*4+2]=v.z; sreg[r4*4+3]=v.w;
            }
        }
        float aq = bq[lane], ak = 0.f, av = 0.f;
        {
            const float4* q4 = (const float4*)(Wq + lane * KD);
            const float4* k4 = (const float4*)(Wk + lane * KD);
            const float4* v4 = (const float4*)(Wv + lane * KD);
            #pragma unroll
            for (int r4 = 0; r4 < 4; ++r4) {
                float4 a = q4[r4], c = k4[r4], d = v4[r4];
                aq = fmaf(sreg[r4*4+0], a.x, aq); ak = fmaf(sreg[r4*4+0], c.x, ak); av = fmaf(sreg[r4*4+0], d.x, av);
                aq = fmaf(sreg[r4*4+1], a.y, aq); ak = fmaf(sreg[r4*4+1], c.y, ak); av = fmaf(sreg[r4*4+1], d.y, av);
                aq = fmaf(sreg[r4*4+2], a.z, aq); ak = fmaf(sreg[r4*4+2], c.z, ak); av = fmaf(sreg[r4*4+2], d.z, av);
                aq = fmaf(sreg[r4*4+3], a.w, aq); ak = fmaf(sreg[r4*4+3], c.w, ak); av = fmaf(sreg[r4*4+3], d.w, av);
            }
        }
        ((float*)(sm + L_Q))[w * 68 + lane] = fmaxf(aq, 0.f) * 0.25f;  // 1/sqrt(16)
        __fp16 hk = (__fp16)ak;
        PkH[(size_t)b * 8192 + iloc * 64 + lane] = *(unsigned short*)&hk;
        __fp16 hv = (__fp16)av;
        PvT[(size_t)b * 8192 + lane * NT + iloc] = *(unsigned short*)&hv;

        // W-pack: 11264 uint4 total = 512 blocks x 22
        if (tid < 22) {
            int fi = bid * 22 + tid;
            if (fi < 3072) {
                int l = fi & 63, rest = fi >> 6;
                int t = rest & 15, ks = rest >> 4;
                int n = t * 16 + (l & 15);
                int kb = ks * 32 + (l >> 4) * 8;
                unsigned short v[8];
                #pragma unroll
                for (int j = 0; j < 8; ++j) {
                    int k = kb + j;
                    v[j] = (k < 80) ? bf16rne(W1[n * 80 + k]) : (unsigned short)0;
                }
                uint4 u;
                u.x = (unsigned)v[0] | ((unsigned)v[1] << 16);
                u.y = (unsigned)v[2] | ((unsigned)v[3] << 16);
                u.z = (unsigned)v[4] | ((unsigned)v[5] << 16);
                u.w = (unsigned)v[6] | ((unsigned)v[7] << 16);
                ((uint4*)(wsb + W1P_OFF))[fi] = u;
            } else {
                int f2 = fi - 3072;
                int l = f2 & 63, rest = f2 >> 6;
                int t = rest & 15, ks = rest >> 4;
                int n = t * 16 + (l & 15);
                int kb = ks * 32 + (l >> 4) * 8;
                unsigned short v[8];
                #pragma unroll
                for (int j = 0; j < 8; ++j) v[j] = bf16rne(W2[n * 256 + kb + j]);
                uint4 u;
                u.x = (unsigned)v[0] | ((unsigned)v[1] << 16);
                u.y = (unsigned)v[2] | ((unsigned)v[3] << 16);
                u.z = (unsigned)v[4] | ((unsigned)v[5] << 16);
                u.w = (unsigned)v[6] | ((unsigned)v[7] << 16);
                ((uint4*)(wsb + W2P_OFF))[fi] = u;
            }
        }
    }
    // input-only prefetches (no dependency on flag)
    float bkf[16];
    {
        const float4* bk4 = (const float4*)(bkg + (h << 4));
        #pragma unroll
        for (int q4 = 0; q4 < 4; ++q4) {
            float4 k4 = bk4[q4];
            bkf[q4*4+0]=k4.x; bkf[q4*4+1]=k4.y; bkf[q4*4+2]=k4.z; bkf[q4*4+3]=k4.w;
        }
    }
    const float bvo = bvg[lane];
    float stt = 0.f;
    if (tid < 128)
        stt = state[((size_t)b * NT + tile * 8 + (tid >> 4)) * KD + (tid & 15)];

    // ======== device-scope flag barrier (all 512 blocks resident by construction) ========
    __syncthreads();                         // all block writes issued
    if (tid == 0) {
        __threadfence();                     // release: publish ws writes device-wide
        __hip_atomic_fetch_add(flagp, 1u, __ATOMIC_RELEASE, __HIP_MEMORY_SCOPE_AGENT);
        while (__hip_atomic_load(flagp, __ATOMIC_ACQUIRE, __HIP_MEMORY_SCOPE_AGENT) < 512u)
            __builtin_amdgcn_s_sleep(2);
        __threadfence();                     // acquire: see all blocks' ws writes
    }
    __syncthreads();

    // ======== PHASE B: R17 actor ========
    // ---- stage Pk f16 [128][72] and Pv f16 [64][136]; pre-zero X rows 8..15 ----
    {
        const uint4* srcK = (const uint4*)(wsb + PKH_OFF) + (size_t)b * 1024;
        #pragma unroll
        for (int it = 0; it < 2; ++it) {
            int idx = tid + it * 512;
            int r = idx >> 3, c = idx & 7;
            *(uint4*)(sm + L_PK + r * 144 + c * 16) = srcK[idx];
        }
        const uint4* srcV = (const uint4*)(wsb + PVT_OFF) + (size_t)b * 1024;
        #pragma unroll
        for (int it = 0; it < 2; ++it) {
            int idx = tid + it * 512;
            int o = idx >> 4, c = idx & 15;
            *(uint4*)(sm + L_PV + o * 272 + c * 16) = srcV[idx];
        }
        if (tid < 384) {
            int r = 8 + tid / 48, c2 = (tid % 48) * 2;
            *(unsigned*)((unsigned short*)(sm + L_X) + r * 104 + c2) = 0u;
        }
    }
    __syncthreads();   // sync1: Pk/Pv staged

    // ---- setup: q8 from LDS f32 (+cvt); mb8 = Pk_i - bk; dotc = sum q*c ----
    f16x2 q8[8], mb8[8];
    float dotc;
    {
        const float* qrow = (const float*)(sm + L_Q) + w * 68 + (h << 4);
        float qf[16];
        #pragma unroll
        for (int k = 0; k < 16; k += 4) {
            float4 t = *(const float4*)(qrow + k);
            qf[k] = t.x; qf[k+1] = t.y; qf[k+2] = t.z; qf[k+3] = t.w;
        }
        U4H8 p0, p1;
        p0.u = *(const uint4*)(sm + L_PK + iloc * 144 + h * 32);
        p1.u = *(const uint4*)(sm + L_PK + iloc * 144 + h * 32 + 16);
        #pragma unroll
        for (int t = 0; t < 4; ++t) {
            q8[t]     = __builtin_amdgcn_cvt_pkrtz(qf[2*t],   qf[2*t+1]);
            q8[4 + t] = __builtin_amdgcn_cvt_pkrtz(qf[8+2*t], qf[8+2*t+1]);
            f16x2 b0 = __builtin_amdgcn_cvt_pkrtz(bkf[2*t],   bkf[2*t+1]);
            f16x2 b1 = __builtin_amdgcn_cvt_pkrtz(bkf[8+2*t], bkf[8+2*t+1]);
            mb8[t]     = p0.h[t] - b0;   // -c = Pk_i - bk
            mb8[4 + t] = p1.h[t] - b1;
        }
        float d0 = 0.f, d1 = 0.f;
        #pragma unroll
        for (int t = 0; t < 4; ++t) {
            d0 = FDOT2(q8[t],     mb8[t],     d0);
            d1 = FDOT2(q8[4 + t], mb8[4 + t], d1);
        }
        dotc = -(d0 + d1);
    }

    // ---- scores: lane (h,s) covers j = s + 16*jj; f16 pkmax + dot2 ----
    float sc[8];
    #pragma unroll
    for (int jj = 0; jj < 8; ++jj) {
        const char* pr = sm + L_PK + (s + (jj << 4)) * 144 + h * 32;
        U4H8 v0, v1;
        v0.u = *(const uint4*)(pr);
        v1.u = *(const uint4*)(pr + 16);
        float aE = 0.f, aO = 0.f;
        #pragma unroll
        for (int t = 0; t < 4; ++t) {
            aE = FDOT2(q8[t],     pkmax(v0.h[t], mb8[t]),     aE);
            aO = FDOT2(q8[4 + t], pkmax(v1.h[t], mb8[4 + t]), aO);
        }
        sc[jj] = dotc + aE + aO;
    }

    // ---- softmax over 128 j within the 16-lane head group ----
    float mx = sc[0];
    #pragma unroll
    for (int jj = 1; jj < 8; ++jj) mx = fmaxf(mx, sc[jj]);
    #pragma unroll
    for (int off = 1; off < 16; off <<= 1) mx = fmaxf(mx, __shfl_xor(mx, off));
    float l = 0.f;
    #pragma unroll
    for (int jj = 0; jj < 8; ++jj) { sc[jj] = __expf(sc[jj] - mx); l += sc[jj]; }
    #pragma unroll
    for (int off = 1; off < 16; off <<= 1) l += __shfl_xor(l, off);
    const float rl = 1.0f / l;
    {
        __fp16* prow = (__fp16*)(sm + L_P) + (w * 4 + h) * 136;
        #pragma unroll
        for (int jj = 0; jj < 8; ++jj) prow[(jj << 4) + s] = (__fp16)sc[jj];
    }
    asm volatile("s_waitcnt lgkmcnt(0)" ::: "memory");   // P row is intra-wave
    __builtin_amdgcn_sched_barrier(0);

    // issue W1P B-frags now: latency hides under PV
    const uint4* W1P = (const uint4*)(wsb + W1P_OFF);
    uint4 w1f0[3], w1f1[3];
    #pragma unroll
    for (int ks = 0; ks < 3; ++ks) {
        w1f0[ks] = W1P[((ks << 4) + t0) * 64 + lane];
        w1f1[ks] = W1P[((ks << 4) + t0 + 1) * 64 + lane];
    }

    // ---- PV packed f16: x = -mbv + rl * sum p~ * max(v, mbv) ----
    float xA;
    {
        const __fp16 pvi = *((const __fp16*)(sm + L_PV) + lane * 136 + iloc);
        const float mbvf = (float)pvi - bvo;
        const __fp16 mbvh = (__fp16)mbvf;
        const f16x2 mbv2 = {mbvh, mbvh};
        const uint4* vrow = (const uint4*)(sm + L_PV + lane * 272);
        const uint4* prow = (const uint4*)(sm + L_P + (w * 4 + h) * 272);
        float acc = 0.f;
        #pragma unroll
        for (int u = 0; u < 16; ++u) {
            U4H8 v; v.u = vrow[u];
            U4H8 p; p.u = prow[u];
            #pragma unroll
            for (int t = 0; t < 4; ++t)
                acc = FDOT2(p.h[t], pkmax(v.h[t], mbv2), acc);
        }
        xA = fmaf(rl, acc, -(float)mbvh);
    }

    // ---- X tile (fresh region, no barrier needed before write) ----
    ((unsigned short*)(sm + L_X))[w * 104 + lane] = bf16rne(xA);
    if (tid < 128) {
        unsigned short* xr = (unsigned short*)(sm + L_X) + (tid >> 4) * 104;
        xr[64 + (tid & 15)] = bf16rne(stt);
        xr[80 + (tid & 15)] = 0;
    }
    __syncthreads();   // syncA: X ready; all Pk/Pv/P reads done -> alias safe

    // ---- layer 1 MFMA (K=96): wave w -> neurons w*32..w*32+31 ----
    const uint4* W2P = (const uint4*)(wsb + W2P_OFF);
    uint4 w2f0[4], w2f1[4];   // ks 0..3 prefetch (lands under L1)
    #pragma unroll
    for (int ks = 0; ks < 4; ++ks) {
        w2f0[ks] = W2P[((ks << 4) + t0) * 64 + lane];
        w2f1[ks] = W2P[((ks << 4) + t0 + 1) * 64 + lane];
    }
    {
        f32x4 a0 = {0.f, 0.f, 0.f, 0.f}, a1 = a0;
        #pragma unroll
        for (int ks = 0; ks < 3; ++ks) {
            U4B8 av; av.u = *(const uint4*)(sm + L_X + (lr * 104 + ks * 32 + g * 8) * 2);
            U4B8 b0; b0.u = w1f0[ks];
            U4B8 b1; b1.u = w1f1[ks];
            a0 = __builtin_amdgcn_mfma_f32_16x16x32_bf16(av.h, b0.h, a0, 0, 0, 0);
            a1 = __builtin_amdgcn_mfma_f32_16x16x32_bf16(av.h, b1.h, a1, 0, 0, 0);
        }
        const float bn0 = b1g[n0], bn1 = b1g[n1];
        #pragma unroll
        for (int qq = 0; qq < 4; ++qq) {
            *((unsigned short*)(sm + L_H1) + (4 * g + qq) * 264 + n0) =
                bf16rne(fmaxf(a0[qq] + bn0, 0.f));
            *((unsigned short*)(sm + L_H1) + (4 * g + qq) * 264 + n1) =
                bf16rne(fmaxf(a1[qq] + bn1, 0.f));
        }
    }
    __syncthreads();   // syncB

    // ---- layer 2 MFMA (K=256): ks0-3 from prefetch, ks4-7 from L2-hot ws ----
    {
        f32x4 a0 = {0.f, 0.f, 0.f, 0.f}, a1 = a0;
        #pragma unroll
        for (int ks = 0; ks < 4; ++ks) {
            U4B8 av; av.u = *(const uint4*)(sm + L_H1 + (lr * 264 + ks * 32 + g * 8) * 2);
            U4B8 b0; b0.u = w2f0[ks];
            U4B8 b1; b1.u = w2f1[ks];
            a0 = __builtin_amdgcn_mfma_f32_16x16x32_bf16(av.h, b0.h, a0, 0, 0, 0);
            a1 = __builtin_amdgcn_mfma_f32_16x16x32_bf16(av.h, b1.h, a1, 0, 0, 0);
        }
        #pragma unroll
        for (int ks = 4; ks < 8; ++ks) {
            U4B8 av; av.u = *(const uint4*)(sm + L_H1 + (lr * 264 + ks * 32 + g * 8) * 2);
            U4B8 b0; b0.u = W2P[((ks << 4) + t0) * 64 + lane];
            U4B8 b1; b1.u = W2P[((ks << 4) + t0 + 1) * 64 + lane];
            a0 = __builtin_amdgcn_mfma_f32_16x16x32_bf16(av.h, b0.h, a0, 0, 0, 0);
            a1 = __builtin_amdgcn_mfma_f32_16x16x32_bf16(av.h, b1.h, a1, 0, 0, 0);
        }
        const float bn0 = b2g[n0], bn1 = b2g[n1];
        #pragma unroll
        for (int qq = 0; qq < 4; ++qq) {
            *((unsigned short*)(sm + L_H2) + (4 * g + qq) * 264 + n0) =
                bf16rne(fmaxf(a0[qq] + bn0, 0.f));
            *((unsigned short*)(sm + L_H2) + (4 * g + qq) * 264 + n1) =
                bf16rne(fmaxf(a1[qq] + bn1, 0.f));
        }
    }
    __syncthreads();   // syncC

    // ---- heads + finalize, fully in-wave (wave w == row m) ----
    {
        const int d = (tid >> 4) & 3, cc = tid & 15;
        const float* wrow = (d < 2) ? (Wmu + d * 256) : (Wls + (d - 2) * 256);
        float hbuf[16];
        uint4 ha = *(const uint4*)(sm + L_H2 + (w * 264 + cc * 16) * 2);
        uint4 hb = *(const uint4*)(sm + L_H2 + (w * 264 + cc * 16 + 8) * 2);
        unpack8(ha, hbuf); unpack8(hb, hbuf + 8);
        float dd = 0.f;
        #pragma unroll
        for (int kk = 0; kk < 16; ++kk)
            dd = fmaf(hbuf[kk], wrow[cc * 16 + kk], dd);
        #pragma unroll
        for (int off = 1; off < 16; off <<= 1) dd += __shfl_xor(dd, off);
        float s0 = __shfl(dd, 0);
        float s1 = __shfl(dd, 16);
        float s2 = __shfl(dd, 32);
        float s3 = __shfl(dd, 48);
        if (lane == 0) {
            const int orow = b * NT + tile * 8 + w;
            float mu0 = tanhf(s0 + bmu[0]);
            float mu1 = tanhf(s1 + bmu[1]);
            float t2  = tanhf(s2 + bls[0]);
            float t3  = tanhf(s3 + bls[1]);
            float ls0 = -20.f + 11.f * (t2 + 1.f);
            float ls1 = -20.f + 11.f * (t3 + 1.f);
            float e0 = eps[orow * 2], e1 = eps[orow * 2 + 1];
            float z0 = mu0 + __expf(ls0) * e0;
            float z1 = mu1 + __expf(ls1) * e1;
            float a0 = tanhf(z0), a1 = tanhf(z1);
            out[orow * 2]     = a0;
            out[orow * 2 + 1] = a1;
            float lp = -0.5f * e0 * e0 - ls0 - 0.91893853320467274f - __logf(1.f - a0 * a0 + 1e-7f)
                     + -0.5f * e1 * e1 - ls1 - 0.91893853320467274f - __logf(1.f - a1 * a1 + 1e-7f);
            out[NB * NT * 2 + orow] = lp;
        }
    }
}

extern "C" void kernel_launch(void* const* d_in, const int* in_sizes, int n_in,
                              void* d_out, int out_size, void* d_ws, size_t ws_size,
                              hipStream_t stream) {
    const float* state = (const float*)d_in[0];
    const float* eps   = (const float*)d_in[1];
    const float* Wq    = (const float*)d_in[2];
    const float* bq    = (const float*)d_in[3];
    const float* Wk    = (const float*)d_in[4];
    const float* bk    = (const float*)d_in[5];
    const float* Wv    = (const float*)d_in[6];
    const float* bv    = (const float*)d_in[7];
    const float* W1    = (const float*)d_in[8];
    const float* b1    = (const float*)d_in[9];
    const float* W2    = (const float*)d_in[10];
    const float* b2    = (const float*)d_in[11];
    const float* Wmu   = (const float*)d_in[12];
    const float* bmu   = (const float*)d_in[13];
    const float* Wls   = (const float*)d_in[14];
    const float* bls   = (const float*)d_in[15];
    float* out = (float*)d_out;
    char* wsb  = (char*)d_ws;

    hipMemsetAsync(wsb + FLAG_OFF, 0, 4, stream);
    actor_kernel<<<512, 512, 0, stream>>>(state, eps, Wq, bq, Wk, bk, Wv, bv,
                                          W1, b1, W2, b2, Wmu, bmu, Wls, bls,
                                          wsb, out);
}

// Round 19
// 20.934 us; speedup vs baseline: 4.8509x; 4.8509x over previous
//
#include <hip/hip_runtime.h>
#include <math.h>

#define NB 32
#define NT 128
#define KD 16

// ws byte offsets
#define QH_OFF   0u          // f16 [4096][64]    512 KB  (relu(q)*0.25)
#define PKH_OFF  524288u     // f16 [32][128][64] 512 KB
#define PVT_OFF  1048576u    // f16 [32][64][128] 512 KB (o-major)
#define MBH_OFF  1572864u    // f16 [4096][64]    512 KB  (Pk_i - bk)
#define DCQ_OFF  2097152u    // f32 [4096][4]     64 KB   (dotc per row,head)
#define W1P_OFF  2162688u    // bf16 MFMA frags [3*16][64] uint4, 48 KB
#define W2P_OFF  2211840u    // bf16 MFMA frags [8*16][64] uint4, 128 KB

typedef float f32x4 __attribute__((ext_vector_type(4)));
typedef short bf16x8 __attribute__((ext_vector_type(8)));
typedef __fp16 f16x2 __attribute__((ext_vector_type(2)));
union U4B8 { uint4 u; bf16x8 h; };
union U4H8 { uint4 u; f16x2 h[4]; };

// actor LDS map (47872 B) -- identical to R12/R17
#define L_PK 0        // f16 [128][72] = 18432 ; aliased by H1/H2 after syncA
#define L_PV 18432    // f16 [64][136] = 17408 (ends 35840)
#define L_P  35840    // f16 [32][136] = 8704  (ends 44544)
#define L_X  44544    // bf16 [16][104] = 3328 (fresh region, ends 47872)
#define L_TOT 47872
#define L_H1 0        // bf16 [16][264] = 8448
#define L_H2 8448     // ends 16896 <= 18432 (inside dead Pk)

__device__ __forceinline__ unsigned short bf16rne(float f) {
    unsigned u = __float_as_uint(f);
    return (unsigned short)((u + 0x7fffu + ((u >> 16) & 1u)) >> 16);
}
__device__ __forceinline__ void unpack8(uint4 u, float* f) {
    f[0] = __uint_as_float(u.x << 16); f[1] = __uint_as_float(u.x & 0xffff0000u);
    f[2] = __uint_as_float(u.y << 16); f[3] = __uint_as_float(u.y & 0xffff0000u);
    f[4] = __uint_as_float(u.z << 16); f[5] = __uint_as_float(u.z & 0xffff0000u);
    f[6] = __uint_as_float(u.w << 16); f[7] = __uint_as_float(u.w & 0xffff0000u);
}
__device__ __forceinline__ f16x2 pkmax(f16x2 a, f16x2 b) {
    f16x2 d;
    asm("v_pk_max_f16 %0, %1, %2" : "=v"(d) : "v"(a), "v"(b));
    return d;
}
#if __has_builtin(__builtin_amdgcn_fdot2)
#define FDOT2(a, b, c) __builtin_amdgcn_fdot2((a), (b), (c), false)
#else
#define FDOT2(a, b, c) ((c) + (float)(a)[0] * (float)(b)[0] + (float)(a)[1] * (float)(b)[1])
#endif

// ---------------- K0: projections (+mb,dotc) + MFMA weight packing ----------------
__global__ __launch_bounds__(256) void prep_kernel(
    const float* __restrict__ state,
    const float* __restrict__ Wq, const float* __restrict__ bq,
    const float* __restrict__ Wk, const float* __restrict__ bkg,
    const float* __restrict__ Wv,
    const float* __restrict__ W1, const float* __restrict__ W2,
    char* __restrict__ wsb)
{
    const int blk = blockIdx.x, tid = threadIdx.x;
    unsigned short* QH  = (unsigned short*)(wsb + QH_OFF);
    unsigned short* PkH = (unsigned short*)(wsb + PKH_OFF);
    unsigned short* PvT = (unsigned short*)(wsb + PVT_OFF);
    unsigned short* MBH = (unsigned short*)(wsb + MBH_OFF);
    float* DCQ = (float*)(wsb + DCQ_OFF);

    if (blk < 128) {
        __shared__ float Wl[3][64][17];
        __shared__ float Sl[32][17];
        const int b = blk >> 2, r0 = (blk & 3) * 32;
        for (int idx = tid; idx < 1024; idx += 256) {
            int o = idx >> 4, m = idx & 15;
            Wl[0][o][m] = Wq[idx];
            Wl[1][o][m] = Wk[idx];
            Wl[2][o][m] = Wv[idx];
        }
        for (int idx = tid; idx < 512; idx += 256)
            Sl[idx >> 4][idx & 15] = state[(size_t)(b * NT + r0) * KD + idx];
        __syncthreads();
        const int o = tid & 63, rr = tid >> 6;
        float wqv[16], wkv[16], wvv[16];
        #pragma unroll
        for (int m = 0; m < 16; ++m) {
            wqv[m] = Wl[0][o][m]; wkv[m] = Wl[1][o][m]; wvv[m] = Wl[2][o][m];
        }
        const float bqo = bq[o], bko = bkg[o];
        for (int r = rr; r < 32; r += 4) {
            float aq = bqo, ak = 0.f, av = 0.f;
            #pragma unroll
            for (int m = 0; m < 16; ++m) {
                float s = Sl[r][m];
                aq = fmaf(s, wqv[m], aq);
                ak = fmaf(s, wkv[m], ak);
                av = fmaf(s, wvv[m], av);
            }
            int row = b * NT + r0 + r;
            float qv = fmaxf(aq, 0.f) * 0.25f;      // 1/sqrt(16) folded
            float mbv = ak - bko;                    // -c = Pk_i - bk
            __fp16 hq = (__fp16)qv;
            QH[row * 64 + o] = *(unsigned short*)&hq;
            __fp16 hk = (__fp16)ak;
            PkH[(size_t)b * 8192 + (r0 + r) * 64 + o] = *(unsigned short*)&hk;
            __fp16 hv = (__fp16)av;
            PvT[(size_t)b * 8192 + o * NT + (r0 + r)] = *(unsigned short*)&hv;
            __fp16 hm = (__fp16)mbv;
            MBH[(size_t)row * 64 + o] = *(unsigned short*)&hm;
            // dotc = -sum_{k in head} q_k * mb_k  (f16-rounded operands, f32 sum)
            float dc = (float)((__fp16)qv) * (float)hm;
            #pragma unroll
            for (int off = 1; off < 16; off <<= 1) dc += __shfl_xor(dc, off);
            if ((o & 15) == 0) DCQ[row * 4 + (o >> 4)] = -dc;
        }
    } else if (blk < 140) {
        int fi = (blk - 128) * 256 + tid;
        int l = fi & 63, rest = fi >> 6;
        int t = rest & 15, ks = rest >> 4;
        int n = t * 16 + (l & 15);
        int kb = ks * 32 + (l >> 4) * 8;
        unsigned short v[8];
        #pragma unroll
        for (int j = 0; j < 8; ++j) {
            int k = kb + j;
            v[j] = (k < 80) ? bf16rne(W1[n * 80 + k]) : (unsigned short)0;
        }
        uint4 u;
        u.x = (unsigned)v[0] | ((unsigned)v[1] << 16);
        u.y = (unsigned)v[2] | ((unsigned)v[3] << 16);
        u.z = (unsigned)v[4] | ((unsigned)v[5] << 16);
        u.w = (unsigned)v[6] | ((unsigned)v[7] << 16);
        ((uint4*)(wsb + W1P_OFF))[fi] = u;
    } else {
        int fi = (blk - 140) * 256 + tid;
        int l = fi & 63, rest = fi >> 6;
        int t = rest & 15, ks = rest >> 4;
        int n = t * 16 + (l & 15);
        int kb = ks * 32 + (l >> 4) * 8;
        unsigned short v[8];
        #pragma unroll
        for (int j = 0; j < 8; ++j) v[j] = bf16rne(W2[n * 256 + kb + j]);
        uint4 u;
        u.x = (unsigned)v[0] | ((unsigned)v[1] << 16);
        u.y = (unsigned)v[2] | ((unsigned)v[3] << 16);
        u.z = (unsigned)v[4] | ((unsigned)v[5] << 16);
        u.w = (unsigned)v[6] | ((unsigned)v[7] << 16);
        ((uint4*)(wsb + W2P_OFF))[fi] = u;
    }
}

// ---------------- K1: 8 rows/block, 512 blocks (R17 + precomputed mb/dotc) ----------------
__global__ __launch_bounds__(512, 4) void actor_kernel(
    const float* __restrict__ state, const float* __restrict__ eps,
    const float* __restrict__ bvg,
    const float* __restrict__ b1g, const float* __restrict__ b2g,
    const float* __restrict__ Wmu, const float* __restrict__ bmu,
    const float* __restrict__ Wls, const float* __restrict__ bls,
    const char* __restrict__ wsb, float* __restrict__ out)
{
    __shared__ __align__(16) char sm[L_TOT];

    const int tid = threadIdx.x, w = tid >> 6, lane = tid & 63;
    const int bid = blockIdx.x;
    const int b    = (bid & 7) * 4 + ((bid >> 3) >> 4);  // batch -> fixed XCD
    const int tile = (bid >> 3) & 15;
    const int iloc = tile * 8 + w;
    const int row  = b * NT + iloc;
    const int h = lane >> 4, s = lane & 15;
    const int g = h, lr = s;
    const int t0 = 2 * w;
    const int n0 = w * 32 + lr, n1 = n0 + 16;

    const unsigned short* QH  = (const unsigned short*)(wsb + QH_OFF);
    const unsigned short* MBH = (const unsigned short*)(wsb + MBH_OFF);
    const float* DCQ = (const float*)(wsb + DCQ_OFF);

    // ---- stage Pk f16 [128][72] and Pv f16 [64][136]; pre-zero X rows 8..15 ----
    {
        const uint4* srcK = (const uint4*)(wsb + PKH_OFF) + (size_t)b * 1024;
        #pragma unroll
        for (int it = 0; it < 2; ++it) {
            int idx = tid + it * 512;
            int r = idx >> 3, c = idx & 7;
            *(uint4*)(sm + L_PK + r * 144 + c * 16) = srcK[idx];
        }
        const uint4* srcV = (const uint4*)(wsb + PVT_OFF) + (size_t)b * 1024;
        #pragma unroll
        for (int it = 0; it < 2; ++it) {
            int idx = tid + it * 512;
            int o = idx >> 4, c = idx & 15;
            *(uint4*)(sm + L_PV + o * 272 + c * 16) = srcV[idx];
        }
        if (tid < 384) {   // zero X rows 8..15 cols 0..95 (fresh region: no hazard)
            int r = 8 + tid / 48, c2 = (tid % 48) * 2;
            *(unsigned*)((unsigned short*)(sm + L_X) + r * 104 + c2) = 0u;
        }
    }

    // ---- global prefetches (q, mb, dotc, state tail) overlap staging ----
    U4H8 qh0, qh1, mh0, mh1;
    qh0.u = *(const uint4*)(QH + (size_t)row * 64 + (h << 4));
    qh1.u = *(const uint4*)(QH + (size_t)row * 64 + (h << 4) + 8);
    mh0.u = *(const uint4*)(MBH + (size_t)row * 64 + (h << 4));
    mh1.u = *(const uint4*)(MBH + (size_t)row * 64 + (h << 4) + 8);
    const float dotc = DCQ[row * 4 + h];
    const float bvo = bvg[lane];
    float stt = 0.f;
    if (tid < 128)
        stt = state[((size_t)b * NT + tile * 8 + (tid >> 4)) * KD + (tid & 15)];
    __syncthreads();   // sync1: Pk/Pv staged

    // ---- setup: pure register unpack (all operands prefetched) ----
    f16x2 q8[8], mb8[8];
    #pragma unroll
    for (int t = 0; t < 4; ++t) {
        q8[t]      = qh0.h[t];
        q8[4 + t]  = qh1.h[t];
        mb8[t]     = mh0.h[t];
        mb8[4 + t] = mh1.h[t];
    }

    // ---- scores: lane (h,s) covers j = s + 16*jj; f16 pkmax + dot2 ----
    float sc[8];
    #pragma unroll
    for (int jj = 0; jj < 8; ++jj) {
        const char* pr = sm + L_PK + (s + (jj << 4)) * 144 + h * 32;
        U4H8 v0, v1;
        v0.u = *(const uint4*)(pr);
        v1.u = *(const uint4*)(pr + 16);
        float aE = 0.f, aO = 0.f;
        #pragma unroll
        for (int t = 0; t < 4; ++t) {
            aE = FDOT2(q8[t],     pkmax(v0.h[t], mb8[t]),     aE);
            aO = FDOT2(q8[4 + t], pkmax(v1.h[t], mb8[4 + t]), aO);
        }
        sc[jj] = dotc + aE + aO;
    }

    // ---- softmax over 128 j within the 16-lane head group ----
    float mx = sc[0];
    #pragma unroll
    for (int jj = 1; jj < 8; ++jj) mx = fmaxf(mx, sc[jj]);
    #pragma unroll
    for (int off = 1; off < 16; off <<= 1) mx = fmaxf(mx, __shfl_xor(mx, off));
    float l = 0.f;
    #pragma unroll
    for (int jj = 0; jj < 8; ++jj) { sc[jj] = __expf(sc[jj] - mx); l += sc[jj]; }
    #pragma unroll
    for (int off = 1; off < 16; off <<= 1) l += __shfl_xor(l, off);
    const float rl = 1.0f / l;
    {
        __fp16* prow = (__fp16*)(sm + L_P) + (w * 4 + h) * 136;
        #pragma unroll
        for (int jj = 0; jj < 8; ++jj) prow[(jj << 4) + s] = (__fp16)sc[jj];
    }
    asm volatile("s_waitcnt lgkmcnt(0)" ::: "memory");   // P row is intra-wave
    __builtin_amdgcn_sched_barrier(0);

    // issue W1P B-frags now: latency hides under PV
    const uint4* W1P = (const uint4*)(wsb + W1P_OFF);
    uint4 w1f0[3], w1f1[3];
    #pragma unroll
    for (int ks = 0; ks < 3; ++ks) {
        w1f0[ks] = W1P[((ks << 4) + t0) * 64 + lane];
        w1f1[ks] = W1P[((ks << 4) + t0 + 1) * 64 + lane];
    }

    // ---- PV packed f16: x = -mbv + rl * sum p~ * max(v, mbv) ----
    float xA;
    {
        const __fp16 pvi = *((const __fp16*)(sm + L_PV) + lane * 136 + iloc);
        const float mbvf = (float)pvi - bvo;
        const __fp16 mbvh = (__fp16)mbvf;
        const f16x2 mbv2 = {mbvh, mbvh};
        const uint4* vrow = (const uint4*)(sm + L_PV + lane * 272);
        const uint4* prow = (const uint4*)(sm + L_P + (w * 4 + h) * 272);
        float acc = 0.f;
        #pragma unroll
        for (int u = 0; u < 16; ++u) {
            U4H8 v; v.u = vrow[u];
            U4H8 p; p.u = prow[u];
            #pragma unroll
            for (int t = 0; t < 4; ++t)
                acc = FDOT2(p.h[t], pkmax(v.h[t], mbv2), acc);
        }
        xA = fmaf(rl, acc, -(float)mbvh);
    }

    // ---- X tile (fresh region, no barrier needed before write) ----
    ((unsigned short*)(sm + L_X))[w * 104 + lane] = bf16rne(xA);
    if (tid < 128) {
        unsigned short* xr = (unsigned short*)(sm + L_X) + (tid >> 4) * 104;
        xr[64 + (tid & 15)] = bf16rne(stt);
        xr[80 + (tid & 15)] = 0;
    }
    __syncthreads();   // syncA: X ready; all Pk/Pv/P reads done -> alias safe

    // ---- layer 1 MFMA (K=96): wave w -> neurons w*32..w*32+31 ----
    const uint4* W2P = (const uint4*)(wsb + W2P_OFF);
    uint4 w2f0[4], w2f1[4];   // ks 0..3 prefetch (lands under L1)
    #pragma unroll
    for (int ks = 0; ks < 4; ++ks) {
        w2f0[ks] = W2P[((ks << 4) + t0) * 64 + lane];
        w2f1[ks] = W2P[((ks << 4) + t0 + 1) * 64 + lane];
    }
    {
        f32x4 a0 = {0.f, 0.f, 0.f, 0.f}, a1 = a0;
        #pragma unroll
        for (int ks = 0; ks < 3; ++ks) {
            U4B8 av; av.u = *(const uint4*)(sm + L_X + (lr * 104 + ks * 32 + g * 8) * 2);
            U4B8 b0; b0.u = w1f0[ks];
            U4B8 b1; b1.u = w1f1[ks];
            a0 = __builtin_amdgcn_mfma_f32_16x16x32_bf16(av.h, b0.h, a0, 0, 0, 0);
            a1 = __builtin_amdgcn_mfma_f32_16x16x32_bf16(av.h, b1.h, a1, 0, 0, 0);
        }
        const float bn0 = b1g[n0], bn1 = b1g[n1];
        #pragma unroll
        for (int qq = 0; qq < 4; ++qq) {
            *((unsigned short*)(sm + L_H1) + (4 * g + qq) * 264 + n0) =
                bf16rne(fmaxf(a0[qq] + bn0, 0.f));
            *((unsigned short*)(sm + L_H1) + (4 * g + qq) * 264 + n1) =
                bf16rne(fmaxf(a1[qq] + bn1, 0.f));
        }
    }
    __syncthreads();   // syncB

    // ---- layer 2 MFMA (K=256): ks0-3 from prefetch, ks4-7 from L2-hot ws ----
    {
        f32x4 a0 = {0.f, 0.f, 0.f, 0.f}, a1 = a0;
        #pragma unroll
        for (int ks = 0; ks < 4; ++ks) {
            U4B8 av; av.u = *(const uint4*)(sm + L_H1 + (lr * 264 + ks * 32 + g * 8) * 2);
            U4B8 b0; b0.u = w2f0[ks];
            U4B8 b1; b1.u = w2f1[ks];
            a0 = __builtin_amdgcn_mfma_f32_16x16x32_bf16(av.h, b0.h, a0, 0, 0, 0);
            a1 = __builtin_amdgcn_mfma_f32_16x16x32_bf16(av.h, b1.h, a1, 0, 0, 0);
        }
        #pragma unroll
        for (int ks = 4; ks < 8; ++ks) {
            U4B8 av; av.u = *(const uint4*)(sm + L_H1 + (lr * 264 + ks * 32 + g * 8) * 2);
            U4B8 b0; b0.u = W2P[((ks << 4) + t0) * 64 + lane];
            U4B8 b1; b1.u = W2P[((ks << 4) + t0 + 1) * 64 + lane];
            a0 = __builtin_amdgcn_mfma_f32_16x16x32_bf16(av.h, b0.h, a0, 0, 0, 0);
            a1 = __builtin_amdgcn_mfma_f32_16x16x32_bf16(av.h, b1.h, a1, 0, 0, 0);
        }
        const float bn0 = b2g[n0], bn1 = b2g[n1];
        #pragma unroll
        for (int qq = 0; qq < 4; ++qq) {
            *((unsigned short*)(sm + L_H2) + (4 * g + qq) * 264 + n0) =
                bf16rne(fmaxf(a0[qq] + bn0, 0.f));
            *((unsigned short*)(sm + L_H2) + (4 * g + qq) * 264 + n1) =
                bf16rne(fmaxf(a1[qq] + bn1, 0.f));
        }
    }
    __syncthreads();   // syncC

    // ---- heads + finalize, fully in-wave (wave w == row m) ----
    {
        const int d = (tid >> 4) & 3, cc = tid & 15;
        const float* wrow = (d < 2) ? (Wmu + d * 256) : (Wls + (d - 2) * 256);
        float hbuf[16];
        uint4 ha = *(const uint4*)(sm + L_H2 + (w * 264 + cc * 16) * 2);
        uint4 hb = *(const uint4*)(sm + L_H2 + (w * 264 + cc * 16 + 8) * 2);
        unpack8(ha, hbuf); unpack8(hb, hbuf + 8);
        float dd = 0.f;
        #pragma unroll
        for (int kk = 0; kk < 16; ++kk)
            dd = fmaf(hbuf[kk], wrow[cc * 16 + kk], dd);
        #pragma unroll
        for (int off = 1; off < 16; off <<= 1) dd += __shfl_xor(dd, off);
        float s0 = __shfl(dd, 0);
        float s1 = __shfl(dd, 16);
        float s2 = __shfl(dd, 32);
        float s3 = __shfl(dd, 48);
        if (lane == 0) {
            const int orow = b * NT + tile * 8 + w;
            float mu0 = tanhf(s0 + bmu[0]);
            float mu1 = tanhf(s1 + bmu[1]);
            float t2  = tanhf(s2 + bls[0]);
            float t3  = tanhf(s3 + bls[1]);
            float ls0 = -20.f + 11.f * (t2 + 1.f);
            float ls1 = -20.f + 11.f * (t3 + 1.f);
            float e0 = eps[orow * 2], e1 = eps[orow * 2 + 1];
            float z0 = mu0 + __expf(ls0) * e0;
            float z1 = mu1 + __expf(ls1) * e1;
            float a0 = tanhf(z0), a1 = tanhf(z1);
            out[orow * 2]     = a0;
            out[orow * 2 + 1] = a1;
            float lp = -0.5f * e0 * e0 - ls0 - 0.91893853320467274f - __logf(1.f - a0 * a0 + 1e-7f)
                     + -0.5f * e1 * e1 - ls1 - 0.91893853320467274f - __logf(1.f - a1 * a1 + 1e-7f);
            out[NB * NT * 2 + orow] = lp;
        }
    }
}

extern "C" void kernel_launch(void* const* d_in, const int* in_sizes, int n_in,
                              void* d_out, int out_size, void* d_ws, size_t ws_size,
                              hipStream_t stream) {
    const float* state = (const float*)d_in[0];
    const float* eps   = (const float*)d_in[1];
    const float* Wq    = (const float*)d_in[2];
    const float* bq    = (const float*)d_in[3];
    const float* Wk    = (const float*)d_in[4];
    const float* bk    = (const float*)d_in[5];
    const float* Wv    = (const float*)d_in[6];
    const float* bv    = (const float*)d_in[7];
    const float* W1    = (const float*)d_in[8];
    const float* b1    = (const float*)d_in[9];
    const float* W2    = (const float*)d_in[10];
    const float* b2    = (const float*)d_in[11];
    const float* Wmu   = (const float*)d_in[12];
    const float* bmu   = (const float*)d_in[13];
    const float* Wls   = (const float*)d_in[14];
    const float* bls   = (const float*)d_in[15];
    float* out = (float*)d_out;
    char* wsb  = (char*)d_ws;

    prep_kernel<<<172, 256, 0, stream>>>(state, Wq, bq, Wk, bk, Wv, W1, W2, wsb);
    actor_kernel<<<512, 512, 0, stream>>>(state, eps, bv, b1, b2,
                                          Wmu, bmu, Wls, bls, wsb, out);
}